// Round 1
// 3472.185 us; speedup vs baseline: 1.3183x; 1.3183x over previous
//
#include <hip/hip_runtime.h>
#include <hip/hip_bf16.h>
#include <cstdint>
#include <cstddef>

typedef _Float16 half8 __attribute__((ext_vector_type(8)));
typedef _Float16 half4 __attribute__((ext_vector_type(4)));
typedef float floatx4 __attribute__((ext_vector_type(4)));

// ---- problem constants ----
// B=128, T=1024, N=256, D=256 for all four GRUs; head 512->128.

// ---- workspace layout (bytes) ----
#define WS_DATA16_OFF   0ull                    // _Float16[128*1024*256]         = 67,108,864 B
#define WS_WKT_OFF      67108864ull             // _Float16[3072*256]             =  1,572,864 B
#define WS_UFRAG_OFF    68681728ull             // _Float16[4*48*8*64*8]          =  1,572,864 B
#define WS_XPF_OFF      70254592ull             // _Float16[4*8*1024*12288]       = 805,306,368 B
#define WS_HLAST_OFF    875560960ull            // float[2*128*256]               =    262,144 B
// total ~875.8 MB

__device__ __forceinline__ void gload_lds16(const void* g, void* l) {
  __builtin_amdgcn_global_load_lds((const __attribute__((address_space(1))) void*)g,
                                   (__attribute__((address_space(3))) void*)l, 16, 0, 0);
}

__device__ __forceinline__ float sigmoidf_(float x) {
  return __builtin_amdgcn_rcpf(1.0f + __expf(-x));
}
__device__ __forceinline__ float tanhf_(float x) {
  return 1.0f - 2.0f * __builtin_amdgcn_rcpf(__expf(2.0f * x) + 1.0f);
}

// ---------------- prep: data fp32 -> fp16 ----------------
__global__ __launch_bounds__(256) void k_cvt_data(const float* __restrict__ src, _Float16* __restrict__ dst) {
  int i = blockIdx.x * 256 + threadIdx.x;          // 8,388,608 threads, 4 elems each
  float4 v = ((const float4*)src)[i];
  half4 h;
  h[0] = (_Float16)v.x; h[1] = (_Float16)v.y; h[2] = (_Float16)v.z; h[3] = (_Float16)v.w;
  *(half4*)(dst + (size_t)i * 4) = h;
}

// ---------------- prep: Wk (4x [256,768]) -> WkT fp16 [3072][256] ----------------
__global__ __launch_bounds__(256) void k_prep_wkt(const float* __restrict__ w0, const float* __restrict__ w1,
                                                  const float* __restrict__ w2, const float* __restrict__ w3,
                                                  _Float16* __restrict__ wkT) {
  int gid = blockIdx.x * 256 + threadIdx.x;        // 98304 = 3072*32
  int k8 = gid & 31;
  int n  = gid >> 5;                               // 0..3071
  int g  = n / 768;
  int j  = n - g * 768;
  const float* W = (g == 0) ? w0 : (g == 1) ? w1 : (g == 2) ? w2 : w3;
  _Float16* o = wkT + (size_t)n * 256 + k8 * 8;
#pragma unroll
  for (int i = 0; i < 8; ++i) o[i] = (_Float16)W[(size_t)(k8 * 8 + i) * 768 + j];
}

// ---------------- prep: U (4x [256,768]) -> MFMA A-fragment order fp16 ----------------
// layout: uf[g][ct(48)][kt(8)][lane(64)][8]; frag elem jj = U[32*kt + 8*q + jj][16*ct + lc]
__global__ __launch_bounds__(256) void k_prep_ufrag(const float* __restrict__ u0, const float* __restrict__ u1,
                                                    const float* __restrict__ u2, const float* __restrict__ u3,
                                                    _Float16* __restrict__ uf) {
  int gid = blockIdx.x * 256 + threadIdx.x;        // 98304 = 4*48*8*64
  int lane = gid & 63;
  int kt = (gid >> 6) & 7;
  int r  = gid >> 9;                               // 0..191
  int ct = r % 48;
  int g  = r / 48;
  int q = lane >> 4, lc = lane & 15;
  const float* U = (g == 0) ? u0 : (g == 1) ? u1 : (g == 2) ? u2 : u3;
  half8 v;
#pragma unroll
  for (int jj = 0; jj < 8; ++jj) v[jj] = (_Float16)U[(size_t)(32 * kt + 8 * q + jj) * 768 + 16 * ct + lc];
  *(half8*)(uf + (size_t)gid * 8) = v;
}

// ---------------- phase 1: xproj^T GEMM ----------------
// C[j(3072)][(b,t)] = WkT[j][k] * data^T[k][(b,t)] + bias[j], written in recurrence fragment order:
// xpf[g][bg][t][jq(192)][b16][4] fp16.  grid: (24 j-tiles, 1024 t-tiles), 256 thr.
__global__ __launch_bounds__(256) void k_gemm_xpf(const _Float16* __restrict__ wkT,
                                                  const _Float16* __restrict__ dat,
                                                  const float* __restrict__ b0, const float* __restrict__ b1,
                                                  const float* __restrict__ b2, const float* __restrict__ b3,
                                                  _Float16* __restrict__ xpf) {
  __shared__ _Float16 As[128 * 64];   // [j-local 128][k 64]
  __shared__ _Float16 Bs[128 * 64];   // [b 128][k 64]
  int tid = threadIdx.x;
  int jt = blockIdx.x;                // 0..23
  int t  = blockIdx.y;                // 0..1023
  int m0 = jt * 128;
  int w = tid >> 6, lane = tid & 63, q = lane >> 4, lc = lane & 15;
  int wm = w >> 1, wn = w & 1;
  floatx4 acc[4][4] = {};
  const char* aBase = (const char*)wkT;
  const char* bBase = (const char*)dat;
  for (int kb = 0; kb < 4; ++kb) {
    int k0 = kb * 64;
#pragma unroll
    for (int i = 0; i < 4; ++i) {
      int fb = tid * 16 + i * 4096;   // flat byte in 16KB tile
      int row = fb >> 7;              // 128B per row (64 fp16)
      int cb  = fb & 127;
      gload_lds16(aBase + (size_t)(m0 + row) * 512 + k0 * 2 + cb,
                  (char*)As + ((tid >> 6) << 10) + i * 4096);
      gload_lds16(bBase + ((size_t)row * 1024 + t) * 512 + k0 * 2 + cb,
                  (char*)Bs + ((tid >> 6) << 10) + i * 4096);
    }
    __syncthreads();
#pragma unroll
    for (int kk = 0; kk < 2; ++kk) {
      half8 af[4], bf[4];
#pragma unroll
      for (int mt = 0; mt < 4; ++mt) af[mt] = *(const half8*)&As[(wm * 64 + mt * 16 + lc) * 64 + kk * 32 + q * 8];
#pragma unroll
      for (int nt = 0; nt < 4; ++nt) bf[nt] = *(const half8*)&Bs[(wn * 64 + nt * 16 + lc) * 64 + kk * 32 + q * 8];
#pragma unroll
      for (int mt = 0; mt < 4; ++mt)
#pragma unroll
        for (int nt = 0; nt < 4; ++nt)
          acc[mt][nt] = __builtin_amdgcn_mfma_f32_16x16x32_f16(af[mt], bf[nt], acc[mt][nt], 0, 0, 0);
    }
    __syncthreads();
  }
  // epilogue: add bias, write fragment-order fp16
  int g = m0 / 768;
  const float* bp = (g == 0) ? b0 : (g == 1) ? b1 : (g == 2) ? b2 : b3;
  int jl0 = (m0 - g * 768) + wm * 64;
#pragma unroll
  for (int mt = 0; mt < 4; ++mt) {
    int jl = jl0 + mt * 16 + 4 * q;                 // feature within g's 768, 4-aligned
    floatx4 bias = *(const floatx4*)&bp[jl];
    int jq = jl >> 2;
#pragma unroll
    for (int nt = 0; nt < 4; ++nt) {
      int bg = 4 * wn + nt;                         // batch group
      size_t chunk = ((size_t)(g * 8 + bg) * 1024 + t) * 12288;
      half4 v;
#pragma unroll
      for (int r = 0; r < 4; ++r) v[r] = (_Float16)(acc[mt][nt][r] + bias[r]);
      *(half4*)&xpf[chunk + (size_t)(jq * 16 + lc) * 4] = v;
    }
  }
}

// ---------------- phase 2: recurrence ----------------
// 32 blocks: g = blk>>3 (0 ic_f, 1 ic_b, 2 ci_f, 3 ci_b), bg = blk&7 (16 batches).
// Transposed orientation: C col = batch (lane&15), C row = feature.
//
// Changes vs previous version (latency-stall removal):
//  * waves_per_eu(2,2): 256-VGPR budget so u1/u2 (192 regs) stay RESIDENT (was 128 -> per-step L2 reloads)
//  * raw s_barrier + counted s_waitcnt: no vmcnt(0) drain per barrier; prefetch & stores stay in flight
//  * 2-step-deep xt prefetch (2 x 48KB buffers): HBM latency gets ~2 full steps of cover
//  * h_s double-buffered: merges the b2/b3 barrier pair -> 2 barriers/step
//  * ci output stored from registers (fp32 pre-round): removes the h_s re-read + its barrier
__global__ __launch_bounds__(512) __attribute__((amdgpu_waves_per_eu(2, 2)))
void k_recur(const _Float16* __restrict__ uf,
             const _Float16* __restrict__ xpf,
             const float* __restrict__ ich0, const float* __restrict__ cih0,
             float* __restrict__ out, float* __restrict__ hlast) {
  __shared__ _Float16 xt[2][2][12288];   // [prefetch buf][step slot][jq(192)][b16][4] : 96 KiB
  __shared__ _Float16 h_s[2][16][264];   // double-buffered hidden state [b][feature], padded
  __shared__ _Float16 rh_s[16][264];
  __shared__ float    z_s[16][260];

  int tid = threadIdx.x;
  int w = tid >> 6, lane = tid & 63, q = lane >> 4, lc = lane & 15;
  int blk = blockIdx.x;
  int g = blk >> 3, bg = blk & 7;
  int b0g = bg * 16;

  // resident weights (fragment order): GEMM1 ct = 4w+nt (zr, j<512); GEMM2 ct = 32+2w+nt (hh)
  half8 u1[4][8], u2[2][8];
#pragma unroll
  for (int nt = 0; nt < 4; ++nt)
#pragma unroll
    for (int kt = 0; kt < 8; ++kt)
      u1[nt][kt] = *(const half8*)(uf + (((size_t)(g * 48 + 4 * w + nt) * 8 + kt) * 64 + lane) * 8);
#pragma unroll
  for (int nt = 0; nt < 2; ++nt)
#pragma unroll
    for (int kt = 0; kt < 8; ++kt)
      u2[nt][kt] = *(const half8*)(uf + (((size_t)(g * 48 + 32 + 2 * w + nt) * 8 + kt) * 64 + lane) * 8);

  // h0
  const float* h0 = (g == 0) ? ich0 : (g == 1) ? ich0 + 256 : (g == 2) ? cih0 : cih0 + 256;
  for (int i = tid; i < 16 * 256; i += 512) {
    int bb = i >> 8, dd = i & 255;
    h_s[0][bb][dd] = (_Float16)h0[dd];
  }
  // zero the CI_LAG pad slots (out is poisoned each call)
  {
    int bb = tid >> 5, c8 = (tid & 31) * 8;
    float4 z4 = {0.f, 0.f, 0.f, 0.f};
    if (g == 2) {
      float* p = out + 32768 + ((size_t)(b0g + bb) * 1024 + 0) * 512 + c8;
      *(float4*)p = z4; *(float4*)(p + 4) = z4;
    } else if (g == 3) {
      float* p = out + 32768 + ((size_t)(b0g + bb) * 1024 + 1023) * 512 + 256 + c8;
      *(float4*)p = z4; *(float4*)(p + 4) = z4;
    }
  }

  bool rev = (g & 1);
  const char* chunk = (const char*)(xpf + (size_t)(g * 8 + bg) * 1024 * 12288);

  // prologue: stage local steps 0,1 into prefetch buffer 0 (6 x 16B per thread = 48KB)
#pragma unroll
  for (int i = 0; i < 6; ++i) {
    int o = tid * 16 + i * 8192;                  // byte within 48KB pair-tile
    int ls = (o >= 24576) ? 1 : 0;                // wave-uniform (boundary is 1KB-aligned)
    int row = rev ? (1023 - ls) : ls;
    gload_lds16(chunk + (size_t)row * 24576 + (o - ls * 24576),
                (char*)xt + ((tid >> 6) << 10) + i * 8192);
  }
  asm volatile("s_waitcnt vmcnt(0) lgkmcnt(0)" ::: "memory");
  __builtin_amdgcn_s_barrier();

  int cur = 0, xb = 0;
  for (int t = 0; t < 1024; ++t) {
    // issue async prefetch of steps t+2,t+3 into the other pair-buffer (every 2nd step)
    if (!(t & 1) && t < 1022) {
      int s = t + 2;
#pragma unroll
      for (int i = 0; i < 6; ++i) {
        int o = tid * 16 + i * 8192;
        int ls = (o >= 24576) ? 1 : 0;
        int row = rev ? (1023 - (s + ls)) : (s + ls);
        gload_lds16(chunk + (size_t)row * 24576 + (o - ls * 24576),
                    (char*)xt + (xb ^ 1) * 49152 + ((tid >> 6) << 10) + i * 8192);
      }
    }
    const _Float16* xcur = &xt[xb][t & 1][0];

    // ---- GEMM1': zr preact, j-tiles ct = 4w+nt ----
    floatx4 acc[4];
#pragma unroll
    for (int nt = 0; nt < 4; ++nt) {
      int ct = 4 * w + nt;
      half4 xv = *(const half4*)&xcur[((ct * 4 + q) * 16 + lc) * 4];
#pragma unroll
      for (int r = 0; r < 4; ++r) acc[nt][r] = (float)xv[r];
    }
#pragma unroll
    for (int kt = 0; kt < 8; ++kt) {
      half8 hb = *(const half8*)&h_s[cur][lc][kt * 32 + q * 8];
#pragma unroll
      for (int nt = 0; nt < 4; ++nt)
        acc[nt] = __builtin_amdgcn_mfma_f32_16x16x32_f16(u1[nt][kt], hb, acc[nt], 0, 0, 0);
    }
    // ---- epi1: waves 0-3 own z (j<256), waves 4-7 own r -> rh ----
    if (w < 4) {
#pragma unroll
      for (int nt = 0; nt < 4; ++nt) {
        int j = 64 * w + 16 * nt + 4 * q;
        floatx4 zv;
#pragma unroll
        for (int r = 0; r < 4; ++r) zv[r] = sigmoidf_(acc[nt][r]);
        *(floatx4*)&z_s[lc][j] = zv;
      }
    } else {
#pragma unroll
      for (int nt = 0; nt < 4; ++nt) {
        int j = 64 * (w - 4) + 16 * nt + 4 * q;
        half4 hv = *(const half4*)&h_s[cur][lc][j];
        half4 rv;
#pragma unroll
        for (int r = 0; r < 4; ++r) rv[r] = (_Float16)(sigmoidf_(acc[nt][r]) * (float)hv[r]);
        *(half4*)&rh_s[lc][j] = rv;
      }
    }
    asm volatile("s_waitcnt lgkmcnt(0)" ::: "memory");
    __builtin_amdgcn_s_barrier();                 // b1: z_s/rh_s visible; prefetch stays in flight

    // ---- GEMM2': hh preact, j-tiles ct = 32+2w+nt ----
    floatx4 acc2[2];
#pragma unroll
    for (int nt = 0; nt < 2; ++nt) {
      int ct = 32 + 2 * w + nt;
      half4 xv = *(const half4*)&xcur[((ct * 4 + q) * 16 + lc) * 4];
#pragma unroll
      for (int r = 0; r < 4; ++r) acc2[nt][r] = (float)xv[r];
    }
#pragma unroll
    for (int kt = 0; kt < 8; ++kt) {
      half8 rb = *(const half8*)&rh_s[lc][kt * 32 + q * 8];
#pragma unroll
      for (int nt = 0; nt < 2; ++nt)
        acc2[nt] = __builtin_amdgcn_mfma_f32_16x16x32_f16(u2[nt][kt], rb, acc2[nt], 0, 0, 0);
    }
    // ---- epi2: h update (fp32 kept for ci store) ----
    half4 hn16[2];
    floatx4 hnf[2];
#pragma unroll
    for (int nt = 0; nt < 2; ++nt) {
      int j = 32 * w + 16 * nt + 4 * q;
      half4 hv = *(const half4*)&h_s[cur][lc][j];
      floatx4 zv = *(const floatx4*)&z_s[lc][j];
#pragma unroll
      for (int r = 0; r < 4; ++r) {
        float th = tanhf_(acc2[nt][r]);
        float v = zv[r] * (float)hv[r] + (1.0f - zv[r]) * th;
        v = fminf(fmaxf(v, -5.0f), 5.0f);
        hnf[nt][r] = v;
        hn16[nt][r] = (_Float16)v;
      }
    }
    // ---- ci sequence output straight from registers (no barrier needed) ----
    if (g >= 2) {
      int trow; bool valid;
      if (g == 2) { trow = t + 1;   valid = (t < 1023); }
      else        { trow = 1022 - t; valid = (t <= 1022); }
      if (valid) {
        float* p = out + 32768 + ((size_t)(b0g + lc) * 1024 + trow) * 512
                 + ((g == 3) ? 256 : 0) + 32 * w + 4 * q;
        *(floatx4*)p = hnf[0];
        *(floatx4*)(p + 16) = hnf[1];
      }
    }
    // write new h into the other buffer
#pragma unroll
    for (int nt = 0; nt < 2; ++nt) {
      int j = 32 * w + 16 * nt + 4 * q;
      *(half4*)&h_s[cur ^ 1][lc][j] = hn16[nt];
    }
    asm volatile("s_waitcnt lgkmcnt(0)" ::: "memory");
    if (t & 1) {
      // before leaving an odd step: the 6 prefetch loads issued at the prior even step
      // must have landed (they feed steps t+1,t+2). Younger outstanding vmem = up to
      // 4 ci stores (2 per step) for g>=2; none for g<2.
      if (g >= 2) asm volatile("s_waitcnt vmcnt(4)" ::: "memory");
      else        asm volatile("s_waitcnt vmcnt(0)" ::: "memory");
    }
    __builtin_amdgcn_s_barrier();                 // b2: new h + (on odd t) fresh xt visible
    cur ^= 1;
    xb ^= (t & 1);
  }
  // ic: final hidden state (after 1024 toggles cur is back to 0)
  if (g < 2) {
    int bb = tid >> 5, c8 = (tid & 31) * 8;
    half8 hv = *(const half8*)&h_s[0][bb][c8];
    float* p = hlast + ((size_t)g * 128 + b0g + bb) * 256 + c8;
#pragma unroll
    for (int r = 0; r < 8; ++r) p[r] = (float)hv[r];
  }
}

// ---------------- head: ic_mean / ic_stddev ----------------
__global__ __launch_bounds__(256) void k_head(const float* __restrict__ hlast,
                                              const float* __restrict__ Wm, const float* __restrict__ bm,
                                              const float* __restrict__ Wl, const float* __restrict__ bl,
                                              float* __restrict__ out) {
  __shared__ float hn[512];
  int b = blockIdx.x, tid = threadIdx.x;
  hn[tid]       = hlast[(size_t)b * 256 + tid];            // forward
  hn[256 + tid] = hlast[32768 + (size_t)b * 256 + tid];    // backward
  __syncthreads();
  if (tid < 128) {
    float a = bm[tid];
    for (int k = 0; k < 512; ++k) a += hn[k] * Wm[(size_t)k * 128 + tid];
    out[b * 128 + tid] = a;
  } else {
    int j = tid - 128;
    float a = bl[j];
    for (int k = 0; k < 512; ++k) a += hn[k] * Wl[(size_t)k * 128 + j];
    out[16384 + b * 128 + j] = sqrtf(__expf(a) + 1e-4f);
  }
}

extern "C" void kernel_launch(void* const* d_in, const int* in_sizes, int n_in,
                              void* d_out, int out_size, void* d_ws, size_t ws_size,
                              hipStream_t stream) {
  const float* data  = (const float*)d_in[0];
  const float* icWkf = (const float*)d_in[1];
  const float* icUf  = (const float*)d_in[2];
  const float* icbf  = (const float*)d_in[3];
  const float* icWkb = (const float*)d_in[4];
  const float* icUb  = (const float*)d_in[5];
  const float* icbb  = (const float*)d_in[6];
  const float* ich0  = (const float*)d_in[7];
  const float* ciWkf = (const float*)d_in[8];
  const float* ciUf  = (const float*)d_in[9];
  const float* cibf  = (const float*)d_in[10];
  const float* ciWkb = (const float*)d_in[11];
  const float* ciUb  = (const float*)d_in[12];
  const float* cibb  = (const float*)d_in[13];
  const float* cih0  = (const float*)d_in[14];
  const float* Wm    = (const float*)d_in[15];
  const float* bm    = (const float*)d_in[16];
  const float* Wl    = (const float*)d_in[17];
  const float* bl    = (const float*)d_in[18];
  float* out = (float*)d_out;
  char* ws = (char*)d_ws;

  _Float16* data16 = (_Float16*)(ws + WS_DATA16_OFF);
  _Float16* wkT    = (_Float16*)(ws + WS_WKT_OFF);
  _Float16* uf     = (_Float16*)(ws + WS_UFRAG_OFF);
  _Float16* xpf    = (_Float16*)(ws + WS_XPF_OFF);
  float*    hlastp = (float*)(ws + WS_HLAST_OFF);

  hipLaunchKernelGGL(k_cvt_data, dim3(32768), dim3(256), 0, stream, data, data16);
  hipLaunchKernelGGL(k_prep_wkt, dim3(384), dim3(256), 0, stream, icWkf, icWkb, ciWkf, ciWkb, wkT);
  hipLaunchKernelGGL(k_prep_ufrag, dim3(384), dim3(256), 0, stream, icUf, icUb, ciUf, ciUb, uf);
  hipLaunchKernelGGL(k_gemm_xpf, dim3(24, 1024), dim3(256), 0, stream,
                     wkT, data16, icbf, icbb, cibf, cibb, xpf);
  hipLaunchKernelGGL(k_recur, dim3(32), dim3(512), 0, stream, uf, xpf, ich0, cih0, out, hlastp);
  hipLaunchKernelGGL(k_head, dim3(128), dim3(256), 0, stream, hlastp, Wm, bm, Wl, bl, out);
}